// Round 7
// baseline (208.211 us; speedup 1.0000x reference)
//
#include <hip/hip_runtime.h>

// Involution: out[b, g*64+c, ho, wo] = sum_{kh,kw} xp[b, g*64+c, ho+kh, wo+kw] * W[b,g,kh,kw,ho,wo]
// B=8, C=512, G=8, cpg=64, H=W=Ho=Wo=64, K=7, PAD=3. fp32.
//
// R9 (2nd resubmit; rounds 5/6 failed on container acquisition - audited:
// kernel cannot hang (no divergent barriers, no loops) and cannot fault
// (all index ranges bounds-checked), so failures are broker-side):
// R8 structure (88us, VGPR 64, FETCH 58MB - L2 locality confirmed) with
// the occupancy knob turned: CHPC 8->4, CSPLIT 8->16.
//   - LDS 32256 -> 16128 B; at VGPR=64 this fits 8 blocks/CU = 32 waves/CU
//     = 100% occupancy (was 3 blocks / 38%).
//   - R8's residual: per-kh weight-load latency (~250cy L2) > per-kh compute
//     (~230cy) and only 12 waves/CU to cross-hide. 8 waves/SIMD at staggered
//     phases hide it by TLP. Pure placement/TLP change; per-block schedule,
//     swizzle, staging all unchanged.
//   - cost: 2x weight-load instruction redundancy (16 channel-splits share a
//     panel) - all L2 hits, ~24us of chip L2 BW hidden under compute.
// Swizzle: per-XCD window = 2 panels (~3.6MB) < 4MB L2.
// R5-R7 lessons stand: no added live state, no manual vmcnt structures.

#define BB 8
#define CC 512
#define GG 8
#define CPG 64
#define HH 64
#define WW 64
#define HW (HH * WW)
#define KK 7
#define PAD 3

#define TILE_ROWS 8
#define CSPLIT 16
#define CHPC 4                           // channels per block
#define LDS_ROWS (TILE_ROWS + KK - 1)    // 14
#define LDS_PITCH 72                     // x col c -> lds col c+4
#define CH_STRIDE (LDS_ROWS * LDS_PITCH) // 1008 words per channel plane
#define NQUADS (LDS_ROWS * (LDS_PITCH / 4))  // 252 quad slots per plane

__global__ __launch_bounds__(256, 8)
void involution_kernel(const float* __restrict__ x,
                       const float* __restrict__ weight,
                       float* __restrict__ out) {
    const int tid = threadIdx.x;
    const int tx = tid & 31;          // wo0 = 2*tx
    const int ty = tid >> 5;          // row within tile

    // ---- XCD-locality decode: all 128 sub-blocks of a (b,g) on one XCD ----
    const int f = blockIdx.x;         // 0..8191
    const int xcd = f & 7;
    const int k = f >> 3;             // 0..1023
    const int bg = ((k >> 7) << 3) + xcd;   // 0..63, bijective
    const int sub = k & 127;          // 0..127
    const int b = bg >> 3;
    const int g = bg & 7;
    const int tile = sub >> 4;        // 0..7
    const int cs = sub & 15;          // 0..15

    const int wo0 = tx << 1;
    const int hbase = tile * TILE_ROWS;
    const int ho = hbase + ty;

    __shared__ float xs[CHPC * CH_STRIDE];   // 16128 B

    // per-pixel weight base: taps at +t*HW, float2 covers wo0,wo0+1
    const float* wq = weight + ((size_t)(b * GG + g) * (KK * KK)) * HW
                    + ho * WW + wo0;

    // staging geometry
    const int sr = tid / 18;              // 0..13 (tid < 252)
    const int sq = tid - sr * 18;         // 0..17
    const int xrow = hbase + sr - PAD;
    const int xcol = sq * 4 - 4;          // -4..64, quad aligned
    const bool sval = (tid < NQUADS)
                   && ((unsigned)xrow < HH) && ((unsigned)xcol < WW);
    const int soff = xrow * WW + xcol;
    const int ldsoff = sr * LDS_PITCH + sq * 4;

    const size_t cbase = (size_t)(b * CC + g * CPG + cs * CHPC) * HW;
    const float* xg = x + cbase;
    float* og = out + cbase + ho * WW + wo0;

    // ---- stage 4 channel planes (register pass-through, dead after write) ----
    float4 q[CHPC];
#pragma unroll
    for (int ch = 0; ch < CHPC; ++ch) {
        float4 v = make_float4(0.f, 0.f, 0.f, 0.f);
        if (sval)
            v = *(const float4*)(xg + (size_t)ch * HW + soff);
        q[ch] = v;
    }
    if (tid < NQUADS) {
#pragma unroll
        for (int ch = 0; ch < CHPC; ++ch)
            *(float4*)(&xs[ch * CH_STRIDE + ldsoff]) = q[ch];
    }
    __syncthreads();                 // planes visible

    // ---- compute: kh outer (7 float2 weights live), ch inner ----
    float acc0[CHPC], acc1[CHPC];
#pragma unroll
    for (int ch = 0; ch < CHPC; ++ch) { acc0[ch] = 0.f; acc1[ch] = 0.f; }

#pragma unroll
    for (int kh = 0; kh < KK; ++kh) {
        __builtin_amdgcn_sched_barrier(0);   // keep loads in their kh step
        float2 wk[KK];
#pragma unroll
        for (int j = 0; j < KK; ++j)
            wk[j] = *(const float2*)(wq + (size_t)(kh * KK + j) * HW);

#pragma unroll
        for (int ch = 0; ch < CHPC; ++ch) {
            const float* row = &xs[ch * CH_STRIDE + (ty + kh) * LDS_PITCH + wo0];
            const float2 p0 = *(const float2*)(row + 0);
            const float2 p1 = *(const float2*)(row + 2);
            const float2 p2 = *(const float2*)(row + 4);
            const float2 p3 = *(const float2*)(row + 6);
            const float2 p4 = *(const float2*)(row + 8);
            const float f1 = p0.y, f2 = p1.x, f3 = p1.y, f4 = p2.x;
            const float f5 = p2.y, f6 = p3.x, f7 = p3.y, f8 = p4.x;
            float a0 = acc0[ch], a1 = acc1[ch];
            a0 = fmaf(f1, wk[0].x, a0);  a1 = fmaf(f2, wk[0].y, a1);
            a0 = fmaf(f2, wk[1].x, a0);  a1 = fmaf(f3, wk[1].y, a1);
            a0 = fmaf(f3, wk[2].x, a0);  a1 = fmaf(f4, wk[2].y, a1);
            a0 = fmaf(f4, wk[3].x, a0);  a1 = fmaf(f5, wk[3].y, a1);
            a0 = fmaf(f5, wk[4].x, a0);  a1 = fmaf(f6, wk[4].y, a1);
            a0 = fmaf(f6, wk[5].x, a0);  a1 = fmaf(f7, wk[5].y, a1);
            a0 = fmaf(f7, wk[6].x, a0);  a1 = fmaf(f8, wk[6].y, a1);
            acc0[ch] = a0; acc1[ch] = a1;
        }
    }

    // ---- store 4 channels x 2 pixels ----
#pragma unroll
    for (int ch = 0; ch < CHPC; ++ch) {
        *(float2*)(og + (size_t)ch * HW)
            = make_float2(acc0[ch], acc1[ch]);
    }
}

extern "C" void kernel_launch(void* const* d_in, const int* in_sizes, int n_in,
                              void* d_out, int out_size, void* d_ws, size_t ws_size,
                              hipStream_t stream) {
    const float* x = (const float*)d_in[0];
    const float* w = (const float*)d_in[1];
    float* out = (float*)d_out;

    dim3 grid((HH / TILE_ROWS) * CSPLIT * GG * BB);   // 8192 blocks, 1D for swizzle
    dim3 block(256);
    involution_kernel<<<grid, block, 0, stream>>>(x, w, out);
}

// Round 8
// 195.270 us; speedup vs baseline: 1.0663x; 1.0663x over previous
//
#include <hip/hip_runtime.h>

// Involution: out[b, g*64+c, ho, wo] = sum_{kh,kw} xp[b, g*64+c, ho+kh, wo+kw] * W[b,g,kh,kw,ho,wo]
// B=8, C=512, G=8, cpg=64, H=W=Ho=Wo=64, K=7, PAD=3. fp32.
//
// R10: attack the LDS pipe. R8/R9 evidence: occupancy 2x (R9) did NOT help
// (88->105us, VALUBusy flat 24%) -> shared-resource bound, and the
// arithmetic says LDS: ~4.6M wave ds_read_b64 + 14.2M conflict cycles
// ~= 127K LDS cycles/CU ~= 53us of a 88-105us kernel (43% conflicts).
// Fix: 4 pixels/thread via 3x ds_read_b128 per (ch,kh):
//   - 3 words/output vs 5 (b64 path); LDS instrs/output 3.3x down.
//   - b128 pattern is bank-uniform: lane start words (8ty+4tx) mod 32 hit
//     each start-bank 8x, each bank serves exactly 8 words (minimum).
//   - weights as float4 (7/kh serving 4px) -> per-output weight-load count
//     halved vs R9 at same 16x redundancy.
// Keeps R8's proven XCD swizzle (64 consecutive blocks per (b,g) panel on
// one XCD; FETCH 124->58MB verified) and sched_barrier-per-kh (prevents
// hoisting all 49 float4 weight loads = 196 regs = R1-R3 spill mode).
// Geometry: 256 thr = 16tx x 16ty, TILE_ROWS=16, CHPC=4, CSPLIT=16.
// LDS 25344B -> 6 blocks/CU. Pressure ~66-70 regs; launch_bounds(256,4)
// caps at 128. Spill tripwire: FETCH/WRITE balloon.

#define BB 8
#define CC 512
#define GG 8
#define CPG 64
#define HH 64
#define WW 64
#define HW (HH * WW)
#define KK 7
#define PAD 3

#define TILE_ROWS 16
#define CSPLIT 16
#define CHPC 4                            // channels per block
#define LDS_ROWS (TILE_ROWS + KK - 1)     // 22
#define LDS_PITCH 72                      // x col c -> lds word c+4
#define CH_STRIDE (LDS_ROWS * LDS_PITCH)  // 1584 words per channel plane
#define PLANE_QUADS (LDS_ROWS * (LDS_PITCH / 4))  // 396
#define TOT_QUADS (CHPC * PLANE_QUADS)    // 1584
#define NPASS ((TOT_QUADS + 255) / 256)   // 7 staging passes

__global__ __launch_bounds__(256, 4)
void involution_kernel(const float* __restrict__ x,
                       const float* __restrict__ weight,
                       float* __restrict__ out) {
    const int tid = threadIdx.x;
    const int tx = tid & 15;          // wo0 = 4*tx
    const int ty = tid >> 4;          // 0..15, row within tile

    // ---- XCD-locality decode: 64 consecutive sub-blocks per (b,g) on one XCD
    const int f = blockIdx.x;         // 0..4095
    const int xcd = f & 7;
    const int k = f >> 3;             // 0..511
    const int bg = ((k >> 6) << 3) + xcd;   // 0..63, bijective
    const int sub = k & 63;           // 0..63
    const int b = bg >> 3;
    const int g = bg & 7;
    const int tile = sub >> 4;        // 0..3
    const int cs = sub & 15;          // 0..15

    const int wo0 = tx << 2;
    const int hbase = tile * TILE_ROWS;
    const int ho = hbase + ty;

    __shared__ float xs[CHPC * CH_STRIDE];   // 25344 B

    // per-pixel weight base: tap t at +t*HW; float4 covers wo0..wo0+3
    const float* wq = weight + ((size_t)(b * GG + g) * (KK * KK)) * HW
                    + ho * WW + wo0;

    const size_t cbase = (size_t)(b * CC + g * CPG + cs * CHPC) * HW;
    const float* xg = x + cbase;
    float* og = out + cbase + ho * WW + wo0;

    // ---- stage 4 channel planes: 1584 quads, 7 masked passes ----
    {
        float4 sv[NPASS];
        int lofs[NPASS];
        bool act[NPASS];
#pragma unroll
        for (int i = 0; i < NPASS; ++i) {
            const int q = tid + i * 256;
            act[i] = (q < TOT_QUADS);
            const int p = q / PLANE_QUADS;        // 0..3 (clamped by act)
            const int r = q - p * PLANE_QUADS;    // 0..395
            const int sr = r / 18;                // 0..21
            const int sq = r - sr * 18;           // 0..17
            const int xrow = hbase + sr - PAD;    // -3..66
            const int xcol = (sq << 2) - 4;       // -4..64
            const bool ld = act[i]
                         && ((unsigned)xrow < HH) && ((unsigned)xcol < WW);
            float4 v = make_float4(0.f, 0.f, 0.f, 0.f);
            if (ld)
                v = *(const float4*)(xg + (size_t)p * HW + xrow * WW + xcol);
            sv[i] = v;
            lofs[i] = p * CH_STRIDE + sr * LDS_PITCH + (sq << 2);
        }
#pragma unroll
        for (int i = 0; i < NPASS; ++i)
            if (act[i]) *(float4*)(&xs[lofs[i]]) = sv[i];
    }
    __syncthreads();                 // planes visible

    // ---- compute: kh outer, 7 float4 weights live, ch inner ----
    float4 acc[CHPC];
#pragma unroll
    for (int ch = 0; ch < CHPC; ++ch)
        acc[ch] = make_float4(0.f, 0.f, 0.f, 0.f);

#pragma unroll
    for (int kh = 0; kh < KK; ++kh) {
        __builtin_amdgcn_sched_barrier(0);   // keep loads in their kh step
        float4 wk[KK];
#pragma unroll
        for (int j = 0; j < KK; ++j)
            wk[j] = *(const float4*)(wq + (size_t)(kh * KK + j) * HW);

#pragma unroll
        for (int ch = 0; ch < CHPC; ++ch) {
            // window: w[i] = col wo0-4+i ; pixel p tap j uses w[p+j+1]
            const float* rowp = &xs[ch * CH_STRIDE + (ty + kh) * LDS_PITCH + wo0];
            const float4 x0 = *(const float4*)(rowp);
            const float4 x1 = *(const float4*)(rowp + 4);
            const float4 x2 = *(const float4*)(rowp + 8);
            const float w1 = x0.y, w2 = x0.z, w3 = x0.w;
            const float w4 = x1.x, w5 = x1.y, w6 = x1.z, w7 = x1.w;
            const float w8 = x2.x, w9 = x2.y, w10 = x2.z;
            float4 a = acc[ch];
            a.x = fmaf(w1, wk[0].x, a.x);  a.y = fmaf(w2, wk[0].y, a.y);
            a.z = fmaf(w3, wk[0].z, a.z);  a.w = fmaf(w4, wk[0].w, a.w);
            a.x = fmaf(w2, wk[1].x, a.x);  a.y = fmaf(w3, wk[1].y, a.y);
            a.z = fmaf(w4, wk[1].z, a.z);  a.w = fmaf(w5, wk[1].w, a.w);
            a.x = fmaf(w3, wk[2].x, a.x);  a.y = fmaf(w4, wk[2].y, a.y);
            a.z = fmaf(w5, wk[2].z, a.z);  a.w = fmaf(w6, wk[2].w, a.w);
            a.x = fmaf(w4, wk[3].x, a.x);  a.y = fmaf(w5, wk[3].y, a.y);
            a.z = fmaf(w6, wk[3].z, a.z);  a.w = fmaf(w7, wk[3].w, a.w);
            a.x = fmaf(w5, wk[4].x, a.x);  a.y = fmaf(w6, wk[4].y, a.y);
            a.z = fmaf(w7, wk[4].z, a.z);  a.w = fmaf(w8, wk[4].w, a.w);
            a.x = fmaf(w6, wk[5].x, a.x);  a.y = fmaf(w7, wk[5].y, a.y);
            a.z = fmaf(w8, wk[5].z, a.z);  a.w = fmaf(w9, wk[5].w, a.w);
            a.x = fmaf(w7, wk[6].x, a.x);  a.y = fmaf(w8, wk[6].y, a.y);
            a.z = fmaf(w9, wk[6].z, a.z);  a.w = fmaf(w10, wk[6].w, a.w);
            acc[ch] = a;
        }
    }

    // ---- store 4 channels x 4 pixels ----
#pragma unroll
    for (int ch = 0; ch < CHPC; ++ch)
        *(float4*)(og + (size_t)ch * HW) = acc[ch];
}

extern "C" void kernel_launch(void* const* d_in, const int* in_sizes, int n_in,
                              void* d_out, int out_size, void* d_ws, size_t ws_size,
                              hipStream_t stream) {
    const float* x = (const float*)d_in[0];
    const float* w = (const float*)d_in[1];
    float* out = (float*)d_out;

    dim3 grid((HH / TILE_ROWS) * CSPLIT * GG * BB);   // 4096 blocks, 1D for swizzle
    dim3 block(256);
    involution_kernel<<<grid, block, 0, stream>>>(x, w, out);
}

// Round 9
// 188.990 us; speedup vs baseline: 1.1017x; 1.0332x over previous
//
#include <hip/hip_runtime.h>

// Involution: out[b, g*64+c, ho, wo] = sum_{kh,kw} xp[b, g*64+c, ho+kh, wo+kw] * W[b,g,kh,kw,ho,wo]
// B=8, C=512, G=8, cpg=64, H=W=Ho=Wo=64, K=7, PAD=3. fp32.
//
// R11: R8 structure (best measured, 88us) with the register budget opened.
// R10 post-mortem: b128 LDS path is WORSE (conflicts 14.2M->29.4M, 95us);
// R8 cycle accounting shows no saturated pipe (LDS 43%, VALU 17%, L2 15%)
// -> still latency-bound on per-kh weight loads (issued right before their
// consuming FMAs; sched_barrier forbade cross-kh overlap; 64-VGPR pin
// forbade buffering). Fix per R7's proven incantation:
//   - __launch_bounds__(256) + amdgpu_waves_per_eu(2,4): allocator budget
//     512/2 = 256 VGPR (R7 measured: delivers >64 VGPR, zero spill).
//   - sched_barrier REMOVED: scheduler may hoist weight loads across kh /
//     to kernel entry. Full hoist = 98 regs weights + 16 acc + temps ~145
//     regs -- fits the budget; the old "hoist = spill disaster" mode no
//     longer exists. Weight latency then overlaps staging + barrier + FMAs.
// Everything else byte-identical to R8: CHPC=8, CSPLIT=8, b64 reads,
// XCD swizzle (FETCH 124->58MB proven), register staging, __syncthreads.
// Tripwires: VGPR stuck at 64 => attr ignored; FETCH/WRITE balloon => spill.

#define BB 8
#define CC 512
#define GG 8
#define CPG 64
#define HH 64
#define WW 64
#define HW (HH * WW)
#define KK 7
#define PAD 3

#define TILE_ROWS 8
#define CSPLIT 8
#define CHPC 8                           // channels per block
#define LDS_ROWS (TILE_ROWS + KK - 1)    // 14
#define LDS_PITCH 72                     // x col c -> lds col c+4
#define CH_STRIDE (LDS_ROWS * LDS_PITCH) // 1008 words per channel plane
#define NQUADS (LDS_ROWS * (LDS_PITCH / 4))  // 252 quad slots per plane

__global__ __launch_bounds__(256)
__attribute__((amdgpu_waves_per_eu(2, 4)))
void involution_kernel(const float* __restrict__ x,
                       const float* __restrict__ weight,
                       float* __restrict__ out) {
    const int tid = threadIdx.x;
    const int tx = tid & 31;          // wo0 = 2*tx
    const int ty = tid >> 5;          // row within tile

    // ---- XCD-locality decode: all 64 sub-blocks of a (b,g) on one XCD ----
    const int f = blockIdx.x;         // 0..4095
    const int xcd = f & 7;
    const int k = f >> 3;             // 0..511
    const int bg = ((k >> 6) << 3) + xcd;   // 0..63, bijective
    const int sub = k & 63;           // 0..63
    const int b = bg >> 3;
    const int g = bg & 7;
    const int tile = sub >> 3;        // 0..7
    const int cs = sub & 7;           // 0..7

    const int wo0 = tx << 1;
    const int hbase = tile * TILE_ROWS;
    const int ho = hbase + ty;

    __shared__ float xs[CHPC * CH_STRIDE];   // 32256 B

    // per-pixel weight base: taps at +t*HW, float2 covers wo0,wo0+1
    const float* wq = weight + ((size_t)(b * GG + g) * (KK * KK)) * HW
                    + ho * WW + wo0;

    // staging geometry
    const int sr = tid / 18;              // 0..13 (tid < 252)
    const int sq = tid - sr * 18;         // 0..17
    const int xrow = hbase + sr - PAD;
    const int xcol = sq * 4 - 4;          // -4..64, quad aligned
    const bool sval = (tid < NQUADS)
                   && ((unsigned)xrow < HH) && ((unsigned)xcol < WW);
    const int soff = xrow * WW + xcol;
    const int ldsoff = sr * LDS_PITCH + sq * 4;

    const size_t cbase = (size_t)(b * CC + g * CPG + cs * CHPC) * HW;
    const float* xg = x + cbase;
    float* og = out + cbase + ho * WW + wo0;

    // ---- stage 8 channel planes (register pass-through, dead after write) ----
    float4 q[CHPC];
#pragma unroll
    for (int ch = 0; ch < CHPC; ++ch) {
        float4 v = make_float4(0.f, 0.f, 0.f, 0.f);
        if (sval)
            v = *(const float4*)(xg + (size_t)ch * HW + soff);
        q[ch] = v;
    }
    if (tid < NQUADS) {
#pragma unroll
        for (int ch = 0; ch < CHPC; ++ch)
            *(float4*)(&xs[ch * CH_STRIDE + ldsoff]) = q[ch];
    }
    __syncthreads();                 // planes visible

    // ---- compute: kh outer (weights free to hoist under 256-reg budget) ----
    float acc0[CHPC], acc1[CHPC];
#pragma unroll
    for (int ch = 0; ch < CHPC; ++ch) { acc0[ch] = 0.f; acc1[ch] = 0.f; }

#pragma unroll
    for (int kh = 0; kh < KK; ++kh) {
        float2 wk[KK];
#pragma unroll
        for (int j = 0; j < KK; ++j)
            wk[j] = *(const float2*)(wq + (size_t)(kh * KK + j) * HW);

#pragma unroll
        for (int ch = 0; ch < CHPC; ++ch) {
            const float* row = &xs[ch * CH_STRIDE + (ty + kh) * LDS_PITCH + wo0];
            const float2 p0 = *(const float2*)(row + 0);
            const float2 p1 = *(const float2*)(row + 2);
            const float2 p2 = *(const float2*)(row + 4);
            const float2 p3 = *(const float2*)(row + 6);
            const float2 p4 = *(const float2*)(row + 8);
            const float f1 = p0.y, f2 = p1.x, f3 = p1.y, f4 = p2.x;
            const float f5 = p2.y, f6 = p3.x, f7 = p3.y, f8 = p4.x;
            float a0 = acc0[ch], a1 = acc1[ch];
            a0 = fmaf(f1, wk[0].x, a0);  a1 = fmaf(f2, wk[0].y, a1);
            a0 = fmaf(f2, wk[1].x, a0);  a1 = fmaf(f3, wk[1].y, a1);
            a0 = fmaf(f3, wk[2].x, a0);  a1 = fmaf(f4, wk[2].y, a1);
            a0 = fmaf(f4, wk[3].x, a0);  a1 = fmaf(f5, wk[3].y, a1);
            a0 = fmaf(f5, wk[4].x, a0);  a1 = fmaf(f6, wk[4].y, a1);
            a0 = fmaf(f6, wk[5].x, a0);  a1 = fmaf(f7, wk[5].y, a1);
            a0 = fmaf(f7, wk[6].x, a0);  a1 = fmaf(f8, wk[6].y, a1);
            acc0[ch] = a0; acc1[ch] = a1;
        }
    }

    // ---- store 8 channels x 2 pixels ----
#pragma unroll
    for (int ch = 0; ch < CHPC; ++ch) {
        *(float2*)(og + (size_t)ch * HW)
            = make_float2(acc0[ch], acc1[ch]);
    }
}

extern "C" void kernel_launch(void* const* d_in, const int* in_sizes, int n_in,
                              void* d_out, int out_size, void* d_ws, size_t ws_size,
                              hipStream_t stream) {
    const float* x = (const float*)d_in[0];
    const float* w = (const float*)d_in[1];
    float* out = (float*)d_out;

    dim3 grid((HH / TILE_ROWS) * CSPLIT * GG * BB);   // 4096 blocks, 1D for swizzle
    dim3 block(256);
    involution_kernel<<<grid, block, 0, stream>>>(x, w, out);
}